// Round 1
// baseline (597.618 us; speedup 1.0000x reference)
//
#include <hip/hip_runtime.h>
#include <stdint.h>

#define NHEAD 16
#define DKH 64
#define BBATCH 4
#define SEQ 2048
#define MROWS (BBATCH*SEQ)   // 8192
#define DMODEL 1024

typedef __attribute__((ext_vector_type(8))) __bf16 bf16x8;
typedef __attribute__((ext_vector_type(4))) float f32x4;

__device__ __forceinline__ unsigned short f2bf(float x) {
  unsigned int u = __float_as_uint(x);
  u += 0x7FFFu + ((u >> 16) & 1u);          // RN-even
  return (unsigned short)(u >> 16);
}
__device__ __forceinline__ float bf2f(unsigned short h) {
  return __uint_as_float(((unsigned int)h) << 16);
}
__device__ __forceinline__ void gl_lds16(const void* g, void* l) {
  __builtin_amdgcn_global_load_lds(
      (const __attribute__((address_space(1))) unsigned int*)g,
      (__attribute__((address_space(3))) unsigned int*)l, 16, 0, 0);
}
__device__ __forceinline__ f32x4 mfma16(bf16x8 a, bf16x8 b, f32x4 c) {
  return __builtin_amdgcn_mfma_f32_16x16x32_bf16(a, b, c, 0, 0, 0);
}

// ---------- fp32 -> bf16 hi/lo split (elementwise) ----------
__global__ __launch_bounds__(256) void split_bf16(
    const float* __restrict__ src, unsigned short* __restrict__ hi,
    unsigned short* __restrict__ lo, int n4, int writeLo) {
  int idx = blockIdx.x * 256 + threadIdx.x;
  int stride = gridDim.x * 256;
  for (int i = idx; i < n4; i += stride) {
    float4 x = ((const float4*)src)[i];
    ushort4 h, l;
    h.x = f2bf(x.x); h.y = f2bf(x.y); h.z = f2bf(x.z); h.w = f2bf(x.w);
    ((ushort4*)hi)[i] = h;
    if (writeLo) {
      l.x = f2bf(x.x - bf2f(h.x));
      l.y = f2bf(x.y - bf2f(h.y));
      l.z = f2bf(x.z - bf2f(h.z));
      l.w = f2bf(x.w - bf2f(h.w));
      ((ushort4*)lo)[i] = l;
    }
  }
}

// ---------- split-precision projection GEMM: Y = X @ W^T ----------
// A (hi/lo) [8192,1024] K-major, B=W (hi/lo) [1024,1024] K-major.
// mode 0: store bf16 to [B,H,S,64] with 0.125 scale (Q)
// mode 1: store bf16 to [B,H,S,64] (K)
// mode 2: store bf16 transposed to [B,H,64,S] (V)
__global__ __launch_bounds__(256) void proj_gemm(
    const unsigned short* __restrict__ Ah, const unsigned short* __restrict__ Al,
    const unsigned short* __restrict__ Bh, const unsigned short* __restrict__ Bl,
    unsigned short* __restrict__ outp, int mode) {
  __shared__ __align__(16) unsigned short smem[16384]; // 32KB
  unsigned short* sAh = smem;
  unsigned short* sAl = smem + 4096;
  unsigned short* sBh = smem + 8192;
  unsigned short* sBl = smem + 12288;
  const int t = threadIdx.x;
  const int bm = blockIdx.x, bn = blockIdx.y;
  const int lane = t & 63, lm = lane & 15, quad = lane >> 4;
  const int w = t >> 6, wr = w >> 1, wc = w & 1;
  const int row = t >> 2, ch = t & 3;

  f32x4 acc[4][4];
#pragma unroll
  for (int i = 0; i < 4; ++i)
#pragma unroll
    for (int j = 0; j < 4; ++j) acc[i][j] = (f32x4){0.f, 0.f, 0.f, 0.f};

  for (int kk = 0; kk < 32; ++kk) {
    int kcol = kk * 32 + ch * 8;
#pragma unroll
    for (int half = 0; half < 2; ++half) {
      int r = half * 64 + row;
      int loff = (half * 256 + t) * 8;
      gl_lds16(Ah + (bm * 128 + r) * 1024 + kcol, sAh + loff);
      gl_lds16(Al + (bm * 128 + r) * 1024 + kcol, sAl + loff);
      gl_lds16(Bh + (bn * 128 + r) * 1024 + kcol, sBh + loff);
      gl_lds16(Bl + (bn * 128 + r) * 1024 + kcol, sBl + loff);
    }
    __syncthreads();   // drains vmcnt before barrier
    bf16x8 ah[4], al[4], bh[4], bl[4];
#pragma unroll
    for (int i = 0; i < 4; ++i) {
      int m = wr * 64 + i * 16 + lm;
      ah[i] = *(const bf16x8*)(sAh + m * 32 + quad * 8);
      al[i] = *(const bf16x8*)(sAl + m * 32 + quad * 8);
      int nn = wc * 64 + i * 16 + lm;
      bh[i] = *(const bf16x8*)(sBh + nn * 32 + quad * 8);
      bl[i] = *(const bf16x8*)(sBl + nn * 32 + quad * 8);
    }
#pragma unroll
    for (int i = 0; i < 4; ++i)
#pragma unroll
      for (int j = 0; j < 4; ++j) {
        acc[i][j] = mfma16(ah[i], bh[j], acc[i][j]);
        acc[i][j] = mfma16(ah[i], bl[j], acc[i][j]);
        acc[i][j] = mfma16(al[i], bh[j], acc[i][j]);
      }
    __syncthreads();
  }

  if (mode < 2) {
    float scale = (mode == 0) ? 0.125f : 1.0f;   // fold 1/sqrt(dk) into Q
#pragma unroll
    for (int i = 0; i < 4; ++i)
#pragma unroll
      for (int j = 0; j < 4; ++j)
#pragma unroll
        for (int r = 0; r < 4; ++r) {
          int m = bm * 128 + wr * 64 + i * 16 + quad * 4 + r;   // token index
          int nn = bn * 128 + wc * 64 + j * 16 + lm;            // feature e
          int b = m >> 11, s = m & 2047, h = nn >> 6, d = nn & 63;
          outp[((b * 16 + h) * 2048 + s) * 64 + d] = f2bf(acc[i][j][r] * scale);
        }
  } else {
    // V: transpose 128x128 tile through LDS, store [B,H,64,S]
#pragma unroll
    for (int i = 0; i < 4; ++i)
#pragma unroll
      for (int j = 0; j < 4; ++j)
#pragma unroll
        for (int r = 0; r < 4; ++r) {
          int ml = wr * 64 + i * 16 + quad * 4 + r;
          int nl = wc * 64 + j * 16 + lm;
          smem[nl * 128 + ml] = f2bf(acc[i][j][r]);
        }
    __syncthreads();
    int nl = t >> 1, half = t & 1;
    int e = bn * 128 + nl, h = e >> 6, d = e & 63;
    int mg = bm * 128;
    int b = mg >> 11, s0 = (mg & 2047) + half * 64;
    const uint4* srcp = (const uint4*)(smem + nl * 128 + half * 64);
    uint4* dstp = (uint4*)(outp + ((b * 16 + h) * 64 + d) * 2048 + s0);
#pragma unroll
    for (int u = 0; u < 8; ++u) dstp[u] = srcp[u];
  }
}

// ---------- flash attention: Q[B,H,S,64], K[B,H,S,64], V^T[B,H,64,S] -> X[B,S,H,64] ----------
__global__ __launch_bounds__(256) void flash_attn(
    const unsigned short* __restrict__ Qw, const unsigned short* __restrict__ Kw,
    const unsigned short* __restrict__ Vt, unsigned short* __restrict__ Xw) {
  __shared__ __align__(16) unsigned short sQ[128 * 64];  // 16KB
  __shared__ __align__(16) unsigned short sK[128 * 64];  // 16KB
  __shared__ __align__(16) unsigned short sV[64 * 128];  // 16KB  [d][s]
  __shared__ __align__(16) unsigned short sP[4 * 32 * 128]; // 32KB wave-private
  const int t = threadIdx.x;
  const int qt = blockIdx.x, bh = blockIdx.y;
  const int lane = t & 63, lm = lane & 15, quad = lane >> 4;
  const int w = t >> 6;
  const unsigned short* gq = Qw + (long)bh * SEQ * 64 + (long)qt * 128 * 64;
#pragma unroll
  for (int is = 0; is < 4; ++is) {
    int cid = is * 256 + t;
    gl_lds16(gq + (cid >> 3) * 64 + (cid & 7) * 8, sQ + cid * 8);
  }
  __syncthreads();
  bf16x8 qf[2][2];
#pragma unroll
  for (int i = 0; i < 2; ++i)
#pragma unroll
    for (int kd = 0; kd < 2; ++kd)
      qf[i][kd] = *(const bf16x8*)(sQ + (w * 32 + i * 16 + lm) * 64 + kd * 32 + quad * 8);

  f32x4 o[2][4];
  float mr[2][4], lr[2][4];
#pragma unroll
  for (int i = 0; i < 2; ++i) {
#pragma unroll
    for (int nv = 0; nv < 4; ++nv) o[i][nv] = (f32x4){0.f, 0.f, 0.f, 0.f};
#pragma unroll
    for (int r = 0; r < 4; ++r) { mr[i][r] = -INFINITY; lr[i][r] = 0.f; }
  }

  for (int kt = 0; kt < 16; ++kt) {
    const unsigned short* gk = Kw + (long)bh * SEQ * 64 + (long)kt * 128 * 64;
    const unsigned short* gv = Vt + (long)bh * 64 * SEQ + kt * 128;
#pragma unroll
    for (int is = 0; is < 4; ++is) {
      int cid = is * 256 + t;
      gl_lds16(gk + (cid >> 3) * 64 + (cid & 7) * 8, sK + cid * 8);
      gl_lds16(gv + (cid >> 4) * SEQ + (cid & 15) * 8, sV + cid * 8);
    }
    __syncthreads();

    f32x4 sc[2][8];
#pragma unroll
    for (int n = 0; n < 8; ++n) {
      bf16x8 kf0 = *(const bf16x8*)(sK + (n * 16 + lm) * 64 + quad * 8);
      bf16x8 kf1 = *(const bf16x8*)(sK + (n * 16 + lm) * 64 + 32 + quad * 8);
#pragma unroll
      for (int i = 0; i < 2; ++i) {
        f32x4 s = (f32x4){0.f, 0.f, 0.f, 0.f};
        s = mfma16(qf[i][0], kf0, s);
        s = mfma16(qf[i][1], kf1, s);
        sc[i][n] = s;
      }
    }

#pragma unroll
    for (int i = 0; i < 2; ++i) {
      f32x4 mx = sc[i][0];
#pragma unroll
      for (int n = 1; n < 8; ++n)
#pragma unroll
        for (int r = 0; r < 4; ++r) mx[r] = fmaxf(mx[r], sc[i][n][r]);
#pragma unroll
      for (int off = 1; off < 16; off <<= 1)
#pragma unroll
        for (int r = 0; r < 4; ++r) {
          float v = mx[r];
          v = fmaxf(v, __shfl_xor(v, off));
          mx[r] = v;
        }
      float alpha[4];
#pragma unroll
      for (int r = 0; r < 4; ++r) {
        float mn = fmaxf(mr[i][r], mx[r]);
        alpha[r] = __builtin_amdgcn_exp2f((mr[i][r] - mn) * 1.44269504f);
        mr[i][r] = mn;
      }
      f32x4 rs = (f32x4){0.f, 0.f, 0.f, 0.f};
#pragma unroll
      for (int n = 0; n < 8; ++n)
#pragma unroll
        for (int r = 0; r < 4; ++r) {
          float p = __builtin_amdgcn_exp2f((sc[i][n][r] - mr[i][r]) * 1.44269504f);
          sc[i][n][r] = p;
          rs[r] += p;
        }
#pragma unroll
      for (int off = 1; off < 16; off <<= 1)
#pragma unroll
        for (int r = 0; r < 4; ++r) rs[r] += __shfl_xor(rs[r], off);
#pragma unroll
      for (int r = 0; r < 4; ++r) lr[i][r] = lr[i][r] * alpha[r] + rs[r];
#pragma unroll
      for (int nv = 0; nv < 4; ++nv)
#pragma unroll
        for (int r = 0; r < 4; ++r) o[i][nv][r] *= alpha[r];
      // P (C-layout) -> LDS for A-operand layout
#pragma unroll
      for (int n = 0; n < 8; ++n)
#pragma unroll
        for (int r = 0; r < 4; ++r)
          sP[w * 4096 + (i * 16 + quad * 4 + r) * 128 + n * 16 + lm] = f2bf(sc[i][n][r]);
    }
    asm volatile("s_waitcnt lgkmcnt(0)" ::: "memory");  // wave-private LDS: no barrier needed
#pragma unroll
    for (int kc = 0; kc < 4; ++kc) {
      bf16x8 pa0 = *(const bf16x8*)(sP + w * 4096 + lm * 128 + kc * 32 + quad * 8);
      bf16x8 pa1 = *(const bf16x8*)(sP + w * 4096 + (16 + lm) * 128 + kc * 32 + quad * 8);
#pragma unroll
      for (int nv = 0; nv < 4; ++nv) {
        bf16x8 vb = *(const bf16x8*)(sV + (nv * 16 + lm) * 128 + kc * 32 + quad * 8);
        o[0][nv] = mfma16(pa0, vb, o[0][nv]);
        o[1][nv] = mfma16(pa1, vb, o[1][nv]);
      }
    }
    __syncthreads();  // protect sK/sV before next stage
  }

  int b = bh >> 4, h = bh & 15;
#pragma unroll
  for (int i = 0; i < 2; ++i)
#pragma unroll
    for (int r = 0; r < 4; ++r) {
      float inv = __builtin_amdgcn_rcpf(lr[i][r]);
      int q = qt * 128 + w * 32 + i * 16 + quad * 4 + r;
#pragma unroll
      for (int nv = 0; nv < 4; ++nv) {
        int d = nv * 16 + lm;
        Xw[((long)(b * 2048 + q) * 16 + h) * 64 + d] = f2bf(o[i][nv][r] * inv);
      }
    }
}

// ---------- output GEMM: out = X @ Wo^T (pure bf16, fp32 out) ----------
__global__ __launch_bounds__(256) void out_gemm(
    const unsigned short* __restrict__ A, const unsigned short* __restrict__ Bw,
    float* __restrict__ C) {
  __shared__ __align__(16) unsigned short smem[8192]; // 16KB
  unsigned short* sA = smem;
  unsigned short* sB = smem + 4096;
  const int t = threadIdx.x;
  const int bm = blockIdx.x, bn = blockIdx.y;
  const int lane = t & 63, lm = lane & 15, quad = lane >> 4;
  const int w = t >> 6, wr = w >> 1, wc = w & 1;
  const int row = t >> 2, ch = t & 3;

  f32x4 acc[4][4];
#pragma unroll
  for (int i = 0; i < 4; ++i)
#pragma unroll
    for (int j = 0; j < 4; ++j) acc[i][j] = (f32x4){0.f, 0.f, 0.f, 0.f};

  for (int kk = 0; kk < 32; ++kk) {
    int kcol = kk * 32 + ch * 8;
#pragma unroll
    for (int half = 0; half < 2; ++half) {
      int r = half * 64 + row;
      int loff = (half * 256 + t) * 8;
      gl_lds16(A + (bm * 128 + r) * 1024 + kcol, sA + loff);
      gl_lds16(Bw + (bn * 128 + r) * 1024 + kcol, sB + loff);
    }
    __syncthreads();
    bf16x8 af[4], bf[4];
#pragma unroll
    for (int i = 0; i < 4; ++i) {
      af[i] = *(const bf16x8*)(sA + (wr * 64 + i * 16 + lm) * 32 + quad * 8);
      bf[i] = *(const bf16x8*)(sB + (wc * 64 + i * 16 + lm) * 32 + quad * 8);
    }
#pragma unroll
    for (int i = 0; i < 4; ++i)
#pragma unroll
      for (int j = 0; j < 4; ++j) acc[i][j] = mfma16(af[i], bf[j], acc[i][j]);
    __syncthreads();
  }
#pragma unroll
  for (int i = 0; i < 4; ++i)
#pragma unroll
    for (int j = 0; j < 4; ++j)
#pragma unroll
      for (int r = 0; r < 4; ++r) {
        int m = bm * 128 + wr * 64 + i * 16 + quad * 4 + r;
        int nn = bn * 128 + wc * 64 + j * 16 + lm;
        C[m * 1024 + nn] = acc[i][j][r];
      }
}

extern "C" void kernel_launch(void* const* d_in, const int* in_sizes, int n_in,
                              void* d_out, int out_size, void* d_ws, size_t ws_size,
                              hipStream_t stream) {
  const float* q  = (const float*)d_in[0];
  const float* k  = (const float*)d_in[1];
  const float* v  = (const float*)d_in[2];
  const float* Wq = (const float*)d_in[3];
  const float* Wk = (const float*)d_in[4];
  const float* Wv = (const float*)d_in[5];
  const float* Wo = (const float*)d_in[6];

  char* ws = (char*)d_ws;
  const size_t MK = (size_t)MROWS * DMODEL;   // 8,388,608 elems
  const size_t KK = (size_t)DMODEL * DMODEL;  // 1,048,576 elems
  size_t off = 0;
  auto nxt = [&](size_t elems) { unsigned short* p = (unsigned short*)(ws + off); off += elems * 2; return p; };
  unsigned short* q_hi = nxt(MK); unsigned short* q_lo = nxt(MK);
  unsigned short* k_hi = nxt(MK); unsigned short* k_lo = nxt(MK);
  unsigned short* v_hi = nxt(MK); unsigned short* v_lo = nxt(MK);
  unsigned short* Wq_hi = nxt(KK); unsigned short* Wq_lo = nxt(KK);
  unsigned short* Wk_hi = nxt(KK); unsigned short* Wk_lo = nxt(KK);
  unsigned short* Wv_hi = nxt(KK); unsigned short* Wv_lo = nxt(KK);
  unsigned short* Wo_hi = nxt(KK);
  unsigned short* Qw = nxt(MK);
  unsigned short* Kw = nxt(MK);
  unsigned short* Vt = nxt(MK);
  unsigned short* Xw = nxt(MK);
  (void)ws_size; (void)in_sizes; (void)n_in; (void)out_size;

  split_bf16<<<8192, 256, 0, stream>>>(q, q_hi, q_lo, (int)(MK / 4), 1);
  split_bf16<<<8192, 256, 0, stream>>>(k, k_hi, k_lo, (int)(MK / 4), 1);
  split_bf16<<<8192, 256, 0, stream>>>(v, v_hi, v_lo, (int)(MK / 4), 1);
  split_bf16<<<1024, 256, 0, stream>>>(Wq, Wq_hi, Wq_lo, (int)(KK / 4), 1);
  split_bf16<<<1024, 256, 0, stream>>>(Wk, Wk_hi, Wk_lo, (int)(KK / 4), 1);
  split_bf16<<<1024, 256, 0, stream>>>(Wv, Wv_hi, Wv_lo, (int)(KK / 4), 1);
  split_bf16<<<1024, 256, 0, stream>>>(Wo, Wo_hi, Wo_hi, (int)(KK / 4), 0);

  dim3 gg(64, 8);
  proj_gemm<<<gg, 256, 0, stream>>>(q_hi, q_lo, Wq_hi, Wq_lo, Qw, 0);
  proj_gemm<<<gg, 256, 0, stream>>>(k_hi, k_lo, Wk_hi, Wk_lo, Kw, 1);
  proj_gemm<<<gg, 256, 0, stream>>>(v_hi, v_lo, Wv_hi, Wv_lo, Vt, 2);
  flash_attn<<<dim3(16, 64), 256, 0, stream>>>(Qw, Kw, Vt, Xw);
  out_gemm<<<gg, 256, 0, stream>>>(Xw, Wo_hi, (float*)d_out);
}

// Round 3
// 483.830 us; speedup vs baseline: 1.2352x; 1.2352x over previous
//
#include <hip/hip_runtime.h>
#include <stdint.h>

#define NHEAD 16
#define DKH 64
#define BBATCH 4
#define SEQ 2048
#define MROWS (BBATCH*SEQ)   // 8192
#define DMODEL 1024

typedef __attribute__((ext_vector_type(8))) __bf16 bf16x8;
typedef __attribute__((ext_vector_type(8))) short s16x8;
typedef __attribute__((ext_vector_type(4))) float f32x4;

__device__ __forceinline__ unsigned short f2bf(float x) {
  unsigned int u = __float_as_uint(x);
  u += 0x7FFFu + ((u >> 16) & 1u);          // RN-even
  return (unsigned short)(u >> 16);
}
__device__ __forceinline__ float bf2f(unsigned short h) {
  return __uint_as_float(((unsigned int)h) << 16);
}
__device__ __forceinline__ void gl_lds16(const void* g, void* l) {
  __builtin_amdgcn_global_load_lds(
      (const __attribute__((address_space(1))) unsigned int*)g,
      (__attribute__((address_space(3))) unsigned int*)l, 16, 0, 0);
}
__device__ __forceinline__ f32x4 mfma16(bf16x8 a, bf16x8 b, f32x4 c) {
  return __builtin_amdgcn_mfma_f32_16x16x32_bf16(a, b, c, 0, 0, 0);
}

// ---------- fp32 -> bf16 hi/lo split (elementwise) ----------
__global__ __launch_bounds__(256) void split_bf16(
    const float* __restrict__ src, unsigned short* __restrict__ hi,
    unsigned short* __restrict__ lo, int n4, int writeLo) {
  int idx = blockIdx.x * 256 + threadIdx.x;
  int stride = gridDim.x * 256;
  for (int i = idx; i < n4; i += stride) {
    float4 x = ((const float4*)src)[i];
    ushort4 h, l;
    h.x = f2bf(x.x); h.y = f2bf(x.y); h.z = f2bf(x.z); h.w = f2bf(x.w);
    ((ushort4*)hi)[i] = h;
    if (writeLo) {
      l.x = f2bf(x.x - bf2f(h.x));
      l.y = f2bf(x.y - bf2f(h.y));
      l.z = f2bf(x.z - bf2f(h.z));
      l.w = f2bf(x.w - bf2f(h.w));
      ((ushort4*)lo)[i] = l;
    }
  }
}

// ---------- split-precision projection GEMM: Y = X @ W^T ----------
// LDS rows of 32 elems, 4 chunks of 8; chunk slot = c ^ ((row>>1)&3) (bank swizzle).
__global__ __launch_bounds__(256) void proj_gemm(
    const unsigned short* __restrict__ Ah, const unsigned short* __restrict__ Al,
    const unsigned short* __restrict__ Bh, const unsigned short* __restrict__ Bl,
    unsigned short* __restrict__ outp, int mode) {
  __shared__ __align__(16) unsigned short smem[16384]; // 32KB
  unsigned short* sAh = smem;
  unsigned short* sAl = smem + 4096;
  unsigned short* sBh = smem + 8192;
  unsigned short* sBl = smem + 12288;
  const int t = threadIdx.x;
  const int bm = blockIdx.x, bn = blockIdx.y;
  const int lane = t & 63, lm = lane & 15, quad = lane >> 4;
  const int w = t >> 6, wr = w >> 1, wc = w & 1;
  const int row = t >> 2, ch = t & 3;
  const int gsw = (t >> 3) & 3;                 // (row>>1)&3
  const int csrc = (ch ^ gsw) * 8;              // source chunk col (elems)
  const int fsw = (lm >> 1) & 3;                // fragment-read swizzle

  f32x4 acc[4][4];
#pragma unroll
  for (int i = 0; i < 4; ++i)
#pragma unroll
    for (int j = 0; j < 4; ++j) acc[i][j] = (f32x4){0.f, 0.f, 0.f, 0.f};

  for (int kk = 0; kk < 32; ++kk) {
    int kcol = kk * 32 + csrc;
#pragma unroll
    for (int half = 0; half < 2; ++half) {
      int r = half * 64 + row;
      int loff = (half * 256 + t) * 8;
      gl_lds16(Ah + (bm * 128 + r) * 1024 + kcol, sAh + loff);
      gl_lds16(Al + (bm * 128 + r) * 1024 + kcol, sAl + loff);
      gl_lds16(Bh + (bn * 128 + r) * 1024 + kcol, sBh + loff);
      gl_lds16(Bl + (bn * 128 + r) * 1024 + kcol, sBl + loff);
    }
    __syncthreads();
    bf16x8 ah[4], al[4], bh[4], bl[4];
#pragma unroll
    for (int i = 0; i < 4; ++i) {
      int m = wr * 64 + i * 16 + lm;
      int co = ((quad ^ fsw) * 8);
      ah[i] = *(const bf16x8*)(sAh + m * 32 + co);
      al[i] = *(const bf16x8*)(sAl + m * 32 + co);
      int nn = wc * 64 + i * 16 + lm;
      bh[i] = *(const bf16x8*)(sBh + nn * 32 + co);
      bl[i] = *(const bf16x8*)(sBl + nn * 32 + co);
    }
#pragma unroll
    for (int i = 0; i < 4; ++i)
#pragma unroll
      for (int j = 0; j < 4; ++j) {
        acc[i][j] = mfma16(ah[i], bh[j], acc[i][j]);
        acc[i][j] = mfma16(ah[i], bl[j], acc[i][j]);
        acc[i][j] = mfma16(al[i], bh[j], acc[i][j]);
      }
    __syncthreads();
  }

  if (mode < 2) {
    // fold 1/sqrt(dk) AND log2(e) into Q so attention uses pure exp2
    float scale = (mode == 0) ? 0.125f * 1.44269504f : 1.0f;
#pragma unroll
    for (int i = 0; i < 4; ++i)
#pragma unroll
      for (int j = 0; j < 4; ++j)
#pragma unroll
        for (int r = 0; r < 4; ++r) {
          int m = bm * 128 + wr * 64 + i * 16 + quad * 4 + r;   // token index
          int nn = bn * 128 + wc * 64 + j * 16 + lm;            // feature e
          int b = m >> 11, s = m & 2047, h = nn >> 6, d = nn & 63;
          outp[((b * 16 + h) * 2048 + s) * 64 + d] = f2bf(acc[i][j][r] * scale);
        }
  } else {
    // V: transpose 128x128 tile through LDS, store [B,H,64,S]
#pragma unroll
    for (int i = 0; i < 4; ++i)
#pragma unroll
      for (int j = 0; j < 4; ++j)
#pragma unroll
        for (int r = 0; r < 4; ++r) {
          int ml = wr * 64 + i * 16 + quad * 4 + r;
          int nl = wc * 64 + j * 16 + lm;
          smem[nl * 128 + ml] = f2bf(acc[i][j][r]);
        }
    __syncthreads();
    int nl = t >> 1, half = t & 1;
    int e = bn * 128 + nl, h = e >> 6, d = e & 63;
    int mg = bm * 128;
    int b = mg >> 11, s0 = (mg & 2047) + half * 64;
    const uint4* srcp = (const uint4*)(smem + nl * 128 + half * 64);
    uint4* dstp = (uint4*)(outp + ((b * 16 + h) * 64 + d) * 2048 + s0);
#pragma unroll
    for (int u = 0; u < 8; ++u) dstp[u] = srcp[u];
  }
}

// ---------- flash attention ----------
// Q[B,H,S,64] (pre-scaled by 0.125*log2e), K[B,H,S,64], V^T[B,H,64,S] -> X[B,S,H,64]
// S^T = K·Q^T with PERMUTED K rows so P exits in the 16x16x32 A-operand layout:
// tile t of pair p reads K row p*32 + 8*(c>>2) + (c&3) + 4t, making lane (Q,c)'s
// C-regs = keys p*32+8Q+{r+4t} for q=c, i.e. A[m=c][k=8Q+j] after packing 2 tiles.
// Direct exp2 (no running max: softmax is shift-invariant, scores can't overflow).
__global__ __launch_bounds__(256, 3) void flash_attn(
    const unsigned short* __restrict__ Qw, const unsigned short* __restrict__ Kw,
    const unsigned short* __restrict__ Vt, unsigned short* __restrict__ Xw) {
  __shared__ __align__(16) unsigned short sQ[128 * 64];  // 16KB, swizzled s(r)
  __shared__ __align__(16) unsigned short sK[128 * 64];  // 16KB, swizzled s(r)
  __shared__ __align__(16) unsigned short sV[64 * 128];  // 16KB, [d][k], ^ (row&15)
  const int t = threadIdx.x;
  const int qt = blockIdx.x, bh = blockIdx.y;
  const int lane = t & 63, lm = lane & 15, quad = lane >> 4;
  const int w = t >> 6;

  const unsigned short* gq = Qw + (long)bh * SEQ * 64 + (long)qt * 128 * 64;
#pragma unroll
  for (int is = 0; is < 4; ++is) {
    int cid = is * 256 + t;
    int r = cid >> 3, cs = cid & 7;
    int sr = (r & 3) | ((r & 8) >> 1);
    gl_lds16(gq + r * 64 + ((cs ^ sr) * 8), sQ + cid * 8);
  }
  __syncthreads();
  bf16x8 qf[2][2];
#pragma unroll
  for (int i = 0; i < 2; ++i)
#pragma unroll
    for (int kc = 0; kc < 2; ++kc) {
      int rq = w * 32 + i * 16 + lm;
      int sq = (rq & 3) | ((rq & 8) >> 1);
      qf[i][kc] = *(const bf16x8*)(sQ + rq * 64 + (((kc * 4 + quad) ^ sq) * 8));
    }

  f32x4 o[2][4];
  float lr[2] = {0.f, 0.f};
#pragma unroll
  for (int i = 0; i < 2; ++i)
#pragma unroll
    for (int nv = 0; nv < 4; ++nv) o[i][nv] = (f32x4){0.f, 0.f, 0.f, 0.f};

  for (int kt = 0; kt < 16; ++kt) {
    const unsigned short* gk = Kw + (long)bh * SEQ * 64 + (long)kt * 128 * 64;
    const unsigned short* gv = Vt + (long)bh * 64 * SEQ + kt * 128;
#pragma unroll
    for (int is = 0; is < 4; ++is) {
      int cid = is * 256 + t;
      int rk = cid >> 3, ck = cid & 7;
      int srk = (rk & 3) | ((rk & 8) >> 1);
      gl_lds16(gk + rk * 64 + ((ck ^ srk) * 8), sK + cid * 8);
      int rv = cid >> 4, cv = cid & 15;
      gl_lds16(gv + rv * SEQ + ((cv ^ (rv & 15)) * 8), sV + cid * 8);
    }
    __syncthreads();

#pragma unroll
    for (int p = 0; p < 4; ++p) {
      // permuted K-row fragment reads (A-operand of S^T)
      bf16x8 kf[2][2];
#pragma unroll
      for (int tt = 0; tt < 2; ++tt) {
        int g = p * 32 + 8 * (lm >> 2) + (lm & 3) + 4 * tt;
        int sg = (g & 3) | ((g & 8) >> 1);
        kf[tt][0] = *(const bf16x8*)(sK + g * 64 + ((quad ^ sg) * 8));
        kf[tt][1] = *(const bf16x8*)(sK + g * 64 + (((4 + quad) ^ sg) * 8));
      }
      bf16x8 pfrag[2];
#pragma unroll
      for (int i = 0; i < 2; ++i) {
        f32x4 s0 = (f32x4){0.f, 0.f, 0.f, 0.f};
        s0 = mfma16(kf[0][0], qf[i][0], s0);
        s0 = mfma16(kf[0][1], qf[i][1], s0);
        f32x4 s1 = (f32x4){0.f, 0.f, 0.f, 0.f};
        s1 = mfma16(kf[1][0], qf[i][0], s1);
        s1 = mfma16(kf[1][1], qf[i][1], s1);
        s16x8 pk;
        float ls = 0.f;
#pragma unroll
        for (int r = 0; r < 4; ++r) {
          float p0 = __builtin_amdgcn_exp2f(s0[r]);
          float p1 = __builtin_amdgcn_exp2f(s1[r]);
          ls += p0 + p1;
          pk[r] = (short)f2bf(p0);
          pk[4 + r] = (short)f2bf(p1);
        }
        lr[i] += ls;
        pfrag[i] = __builtin_bit_cast(bf16x8, pk);
      }
      // PV: o[q][d] += P[q][k]·V[k][d], K=32, P straight from registers
#pragma unroll
      for (int nv = 0; nv < 4; ++nv) {
        bf16x8 vb = *(const bf16x8*)(sV + (nv * 16 + lm) * 128 + (((p * 4 + quad) ^ lm) * 8));
        o[0][nv] = mfma16(pfrag[0], vb, o[0][nv]);
        o[1][nv] = mfma16(pfrag[1], vb, o[1][nv]);
      }
    }
    __syncthreads();
  }

  int b = bh >> 4, h = bh & 15;
#pragma unroll
  for (int i = 0; i < 2; ++i) {
    float ls = lr[i];
    ls += __shfl_xor(ls, 16);
    ls += __shfl_xor(ls, 32);
    float inv[4];
#pragma unroll
    for (int r = 0; r < 4; ++r)
      inv[r] = __builtin_amdgcn_rcpf(__shfl(ls, quad * 4 + r));
#pragma unroll
    for (int nv = 0; nv < 4; ++nv)
#pragma unroll
      for (int r = 0; r < 4; ++r) {
        int q = qt * 128 + w * 32 + i * 16 + quad * 4 + r;
        int d = nv * 16 + lm;
        Xw[((long)(b * 2048 + q) * 16 + h) * 64 + d] = f2bf(o[i][nv][r] * inv[r]);
      }
  }
}

// ---------- output GEMM: out = X @ Wo^T (pure bf16, fp32 out) ----------
__global__ __launch_bounds__(256) void out_gemm(
    const unsigned short* __restrict__ A, const unsigned short* __restrict__ Bw,
    float* __restrict__ C) {
  __shared__ __align__(16) unsigned short smem[8192]; // 16KB
  unsigned short* sA = smem;
  unsigned short* sB = smem + 4096;
  const int t = threadIdx.x;
  const int bm = blockIdx.x, bn = blockIdx.y;
  const int lane = t & 63, lm = lane & 15, quad = lane >> 4;
  const int w = t >> 6, wr = w >> 1, wc = w & 1;
  const int row = t >> 2, ch = t & 3;
  const int csrc = ((ch ^ ((t >> 3) & 3)) * 8);
  const int fsw = (lm >> 1) & 3;

  f32x4 acc[4][4];
#pragma unroll
  for (int i = 0; i < 4; ++i)
#pragma unroll
    for (int j = 0; j < 4; ++j) acc[i][j] = (f32x4){0.f, 0.f, 0.f, 0.f};

  for (int kk = 0; kk < 32; ++kk) {
    int kcol = kk * 32 + csrc;
#pragma unroll
    for (int half = 0; half < 2; ++half) {
      int r = half * 64 + row;
      int loff = (half * 256 + t) * 8;
      gl_lds16(A + (bm * 128 + r) * 1024 + kcol, sA + loff);
      gl_lds16(Bw + (bn * 128 + r) * 1024 + kcol, sB + loff);
    }
    __syncthreads();
    bf16x8 af[4], bf[4];
#pragma unroll
    for (int i = 0; i < 4; ++i) {
      int co = ((quad ^ fsw) * 8);
      af[i] = *(const bf16x8*)(sA + (wr * 64 + i * 16 + lm) * 32 + co);
      bf[i] = *(const bf16x8*)(sB + (wc * 64 + i * 16 + lm) * 32 + co);
    }
#pragma unroll
    for (int i = 0; i < 4; ++i)
#pragma unroll
      for (int j = 0; j < 4; ++j) acc[i][j] = mfma16(af[i], bf[j], acc[i][j]);
    __syncthreads();
  }
#pragma unroll
  for (int i = 0; i < 4; ++i)
#pragma unroll
    for (int j = 0; j < 4; ++j)
#pragma unroll
      for (int r = 0; r < 4; ++r) {
        int m = bm * 128 + wr * 64 + i * 16 + quad * 4 + r;
        int nn = bn * 128 + wc * 64 + j * 16 + lm;
        C[m * 1024 + nn] = acc[i][j][r];
      }
}

extern "C" void kernel_launch(void* const* d_in, const int* in_sizes, int n_in,
                              void* d_out, int out_size, void* d_ws, size_t ws_size,
                              hipStream_t stream) {
  const float* q  = (const float*)d_in[0];
  const float* k  = (const float*)d_in[1];
  const float* v  = (const float*)d_in[2];
  const float* Wq = (const float*)d_in[3];
  const float* Wk = (const float*)d_in[4];
  const float* Wv = (const float*)d_in[5];
  const float* Wo = (const float*)d_in[6];

  char* ws = (char*)d_ws;
  const size_t MK = (size_t)MROWS * DMODEL;   // 8,388,608 elems
  const size_t KK = (size_t)DMODEL * DMODEL;  // 1,048,576 elems
  size_t off = 0;
  auto nxt = [&](size_t elems) { unsigned short* p = (unsigned short*)(ws + off); off += elems * 2; return p; };
  unsigned short* q_hi = nxt(MK); unsigned short* q_lo = nxt(MK);
  unsigned short* k_hi = nxt(MK); unsigned short* k_lo = nxt(MK);
  unsigned short* v_hi = nxt(MK); unsigned short* v_lo = nxt(MK);
  unsigned short* Wq_hi = nxt(KK); unsigned short* Wq_lo = nxt(KK);
  unsigned short* Wk_hi = nxt(KK); unsigned short* Wk_lo = nxt(KK);
  unsigned short* Wv_hi = nxt(KK); unsigned short* Wv_lo = nxt(KK);
  unsigned short* Wo_hi = nxt(KK);
  unsigned short* Qw = nxt(MK);
  unsigned short* Kw = nxt(MK);
  unsigned short* Vt = nxt(MK);
  unsigned short* Xw = nxt(MK);
  (void)ws_size; (void)in_sizes; (void)n_in; (void)out_size;

  split_bf16<<<8192, 256, 0, stream>>>(q, q_hi, q_lo, (int)(MK / 4), 1);
  split_bf16<<<8192, 256, 0, stream>>>(k, k_hi, k_lo, (int)(MK / 4), 1);
  split_bf16<<<8192, 256, 0, stream>>>(v, v_hi, v_lo, (int)(MK / 4), 1);
  split_bf16<<<1024, 256, 0, stream>>>(Wq, Wq_hi, Wq_lo, (int)(KK / 4), 1);
  split_bf16<<<1024, 256, 0, stream>>>(Wk, Wk_hi, Wk_lo, (int)(KK / 4), 1);
  split_bf16<<<1024, 256, 0, stream>>>(Wv, Wv_hi, Wv_lo, (int)(KK / 4), 1);
  split_bf16<<<1024, 256, 0, stream>>>(Wo, Wo_hi, Wo_hi, (int)(KK / 4), 0);

  dim3 gg(64, 8);
  proj_gemm<<<gg, 256, 0, stream>>>(q_hi, q_lo, Wq_hi, Wq_lo, Qw, 0);
  proj_gemm<<<gg, 256, 0, stream>>>(k_hi, k_lo, Wk_hi, Wk_lo, Kw, 1);
  proj_gemm<<<gg, 256, 0, stream>>>(v_hi, v_lo, Wv_hi, Wv_lo, Vt, 2);
  flash_attn<<<dim3(16, 64), 256, 0, stream>>>(Qw, Kw, Vt, Xw);
  out_gemm<<<gg, 256, 0, stream>>>(Xw, Wo_hi, (float*)d_out);
}

// Round 4
// 391.747 us; speedup vs baseline: 1.5255x; 1.2351x over previous
//
#include <hip/hip_runtime.h>
#include <stdint.h>

#define NHEAD 16
#define DKH 64
#define BBATCH 4
#define SEQ 2048
#define MROWS (BBATCH*SEQ)   // 8192
#define DMODEL 1024

typedef __attribute__((ext_vector_type(8))) __bf16 bf16x8;
typedef __attribute__((ext_vector_type(4))) float f32x4;

__device__ __forceinline__ unsigned short f2bf(float x) {
  unsigned int u = __float_as_uint(x);
  u += 0x7FFFu + ((u >> 16) & 1u);          // RN-even
  return (unsigned short)(u >> 16);
}
// pack bf16(a) | bf16(b)<<16, round-half-up: 2 adds + 1 v_perm
__device__ __forceinline__ unsigned int pkbf(float a, float b) {
  return __builtin_amdgcn_perm(__float_as_uint(b) + 0x8000u,
                               __float_as_uint(a) + 0x8000u, 0x07060302u);
}
__device__ __forceinline__ void gl_lds16(const void* g, void* l) {
  __builtin_amdgcn_global_load_lds(
      (const __attribute__((address_space(1))) unsigned int*)g,
      (__attribute__((address_space(3))) unsigned int*)l, 16, 0, 0);
}
__device__ __forceinline__ f32x4 mfma16(bf16x8 a, bf16x8 b, f32x4 c) {
  return __builtin_amdgcn_mfma_f32_16x16x32_bf16(a, b, c, 0, 0, 0);
}

// ---------- fused fp32 -> bf16 convert for all 7 tensors ----------
__global__ __launch_bounds__(256) void cvt_all(
    const float* __restrict__ s0, const float* __restrict__ s1,
    const float* __restrict__ s2, const float* __restrict__ s3,
    const float* __restrict__ s4, const float* __restrict__ s5,
    const float* __restrict__ s6,
    unsigned short* __restrict__ d0, unsigned short* __restrict__ d1,
    unsigned short* __restrict__ d2, unsigned short* __restrict__ d3,
    unsigned short* __restrict__ d4, unsigned short* __restrict__ d5,
    unsigned short* __restrict__ d6) {
  const int NB = 2097152;   // float4 groups in q/k/v
  const int NW = 262144;    // float4 groups in each W
  int i = blockIdx.x * 256 + threadIdx.x;
  const float* src; unsigned short* dst; int off;
  if      (i < NB)          { src = s0; dst = d0; off = i; }
  else if (i < 2*NB)        { src = s1; dst = d1; off = i - NB; }
  else if (i < 3*NB)        { src = s2; dst = d2; off = i - 2*NB; }
  else if (i < 3*NB + NW)   { src = s3; dst = d3; off = i - 3*NB; }
  else if (i < 3*NB + 2*NW) { src = s4; dst = d4; off = i - 3*NB - NW; }
  else if (i < 3*NB + 3*NW) { src = s5; dst = d5; off = i - 3*NB - 2*NW; }
  else                      { src = s6; dst = d6; off = i - 3*NB - 3*NW; }
  float4 x = ((const float4*)src)[off];
  uint2 o; o.x = pkbf(x.x, x.y); o.y = pkbf(x.z, x.w);
  ((uint2*)dst)[off] = o;
}

// ---------- fused Q/K/V projection GEMM: Y = X @ W^T (pure bf16) ----------
// z=0: Q -> [B,H,S,64] scaled by 0.125*log2e; z=1: K -> [B,H,S,64];
// z=2: V -> transposed [B,H,64,S].
__global__ __launch_bounds__(256) void proj_gemm(
    const unsigned short* __restrict__ A0, const unsigned short* __restrict__ A1,
    const unsigned short* __restrict__ A2,
    const unsigned short* __restrict__ B0, const unsigned short* __restrict__ B1,
    const unsigned short* __restrict__ B2,
    unsigned short* __restrict__ O0, unsigned short* __restrict__ O1,
    unsigned short* __restrict__ O2) {
  __shared__ __align__(16) unsigned short smem[16384]; // 32KB (transpose scratch in z=2)
  unsigned short* sA = smem;
  unsigned short* sB = smem + 4096;
  const int z = blockIdx.z;
  const unsigned short* Ah = (z == 0) ? A0 : ((z == 1) ? A1 : A2);
  const unsigned short* Bh = (z == 0) ? B0 : ((z == 1) ? B1 : B2);
  unsigned short* outp = (z == 0) ? O0 : ((z == 1) ? O1 : O2);
  const int t = threadIdx.x;
  const int bm = blockIdx.x, bn = blockIdx.y;
  const int lane = t & 63, lm = lane & 15, quad = lane >> 4;
  const int w = t >> 6, wr = w >> 1, wc = w & 1;
  const int row = t >> 2, ch = t & 3;
  const int csrc = ((ch ^ ((t >> 3) & 3)) * 8);  // staging swizzle
  const int fsw = (lm >> 1) & 3;                 // fragment-read swizzle

  f32x4 acc[4][4];
#pragma unroll
  for (int i = 0; i < 4; ++i)
#pragma unroll
    for (int j = 0; j < 4; ++j) acc[i][j] = (f32x4){0.f, 0.f, 0.f, 0.f};

  for (int kk = 0; kk < 32; ++kk) {
    int kcol = kk * 32 + csrc;
#pragma unroll
    for (int half = 0; half < 2; ++half) {
      int r = half * 64 + row;
      int loff = (half * 256 + t) * 8;
      gl_lds16(Ah + (bm * 128 + r) * 1024 + kcol, sA + loff);
      gl_lds16(Bh + (bn * 128 + r) * 1024 + kcol, sB + loff);
    }
    __syncthreads();
    bf16x8 af[4], bf[4];
#pragma unroll
    for (int i = 0; i < 4; ++i) {
      int co = ((quad ^ fsw) * 8);
      af[i] = *(const bf16x8*)(sA + (wr * 64 + i * 16 + lm) * 32 + co);
      bf[i] = *(const bf16x8*)(sB + (wc * 64 + i * 16 + lm) * 32 + co);
    }
#pragma unroll
    for (int i = 0; i < 4; ++i)
#pragma unroll
      for (int j = 0; j < 4; ++j) acc[i][j] = mfma16(af[i], bf[j], acc[i][j]);
    __syncthreads();
  }

  if (z < 2) {
    float scale = (z == 0) ? 0.125f * 1.44269504f : 1.0f;
#pragma unroll
    for (int i = 0; i < 4; ++i)
#pragma unroll
      for (int j = 0; j < 4; ++j)
#pragma unroll
        for (int r = 0; r < 4; ++r) {
          int m = bm * 128 + wr * 64 + i * 16 + quad * 4 + r;   // token
          int nn = bn * 128 + wc * 64 + j * 16 + lm;            // feature
          int b = m >> 11, s = m & 2047, h = nn >> 6, d = nn & 63;
          outp[((b * 16 + h) * 2048 + s) * 64 + d] = f2bf(acc[i][j][r] * scale);
        }
  } else {
    // V: transpose 128x128 tile through LDS, store [B,H,64,S]
    __syncthreads();
#pragma unroll
    for (int i = 0; i < 4; ++i)
#pragma unroll
      for (int j = 0; j < 4; ++j)
#pragma unroll
        for (int r = 0; r < 4; ++r) {
          int ml = wr * 64 + i * 16 + quad * 4 + r;
          int nl = wc * 64 + j * 16 + lm;
          smem[nl * 128 + ml] = f2bf(acc[i][j][r]);
        }
    __syncthreads();
    int nl = t >> 1, half = t & 1;
    int e = bn * 128 + nl, h = e >> 6, d = e & 63;
    int mg = bm * 128;
    int b = mg >> 11, s0 = (mg & 2047) + half * 64;
    const uint4* srcp = (const uint4*)(smem + nl * 128 + half * 64);
    uint4* dstp = (uint4*)(outp + ((b * 16 + h) * 64 + d) * 2048 + s0);
#pragma unroll
    for (int u = 0; u < 8; ++u) dstp[u] = srcp[u];
  }
}

// ---------- flash attention ----------
// Q[B,H,S,64] (pre-scaled by 0.125*log2e), K[B,H,S,64], V^T[B,H,64,S] -> X[B,S,H,64]
// grid (bh, qt): blocks sharing a K/V slab are 64 apart in linear id -> same XCD.
// S^T = K·Q^T with permuted K rows so P exits in the 16x16x32 A-operand layout.
// Direct exp2 (softmax shift-invariance; scores can't overflow fp32).
__global__ __launch_bounds__(256, 4) void flash_attn(
    const unsigned short* __restrict__ Qw, const unsigned short* __restrict__ Kw,
    const unsigned short* __restrict__ Vt, unsigned short* __restrict__ Xw) {
  __shared__ __align__(16) unsigned short sK[128 * 64];  // 16KB, swizzled s(r)
  __shared__ __align__(16) unsigned short sV[64 * 128];  // 16KB, [d][k], ^(row&15)
  const int t = threadIdx.x;
  const int bh = blockIdx.x, qt = blockIdx.y;
  const int lane = t & 63, lm = lane & 15, quad = lane >> 4;
  const int w = t >> 6;

  // Q fragments straight from global (one-time, 64B/lane)
  const unsigned short* gq = Qw + (long)bh * SEQ * 64 + (long)qt * 128 * 64;
  bf16x8 qf[2][2];
#pragma unroll
  for (int i = 0; i < 2; ++i)
#pragma unroll
    for (int kc = 0; kc < 2; ++kc)
      qf[i][kc] = *(const bf16x8*)(gq + (w * 32 + i * 16 + lm) * 64 + kc * 32 + quad * 8);

  f32x4 o[2][4];
  float lr[2] = {0.f, 0.f};
#pragma unroll
  for (int i = 0; i < 2; ++i)
#pragma unroll
    for (int nv = 0; nv < 4; ++nv) o[i][nv] = (f32x4){0.f, 0.f, 0.f, 0.f};

  for (int kt = 0; kt < 16; ++kt) {
    const unsigned short* gk = Kw + (long)bh * SEQ * 64 + (long)kt * 128 * 64;
    const unsigned short* gv = Vt + (long)bh * 64 * SEQ + kt * 128;
#pragma unroll
    for (int is = 0; is < 4; ++is) {
      int cid = is * 256 + t;
      int rk = cid >> 3, ck = cid & 7;
      int srk = (rk & 3) | ((rk & 8) >> 1);
      gl_lds16(gk + rk * 64 + ((ck ^ srk) * 8), sK + cid * 8);
      int rv = cid >> 4, cv = cid & 15;
      gl_lds16(gv + rv * SEQ + ((cv ^ (rv & 15)) * 8), sV + cid * 8);
    }
    __syncthreads();

#pragma unroll
    for (int p = 0; p < 4; ++p) {
      // permuted K-row fragment reads (A-operand of S^T)
      bf16x8 kf[2][2];
#pragma unroll
      for (int tt = 0; tt < 2; ++tt) {
        int g = p * 32 + 8 * (lm >> 2) + (lm & 3) + 4 * tt;
        int sg = (g & 3) | ((g & 8) >> 1);
        kf[tt][0] = *(const bf16x8*)(sK + g * 64 + ((quad ^ sg) * 8));
        kf[tt][1] = *(const bf16x8*)(sK + g * 64 + (((4 + quad) ^ sg) * 8));
      }
      bf16x8 pfrag[2];
#pragma unroll
      for (int i = 0; i < 2; ++i) {
        f32x4 s0 = (f32x4){0.f, 0.f, 0.f, 0.f};
        s0 = mfma16(kf[0][0], qf[i][0], s0);
        s0 = mfma16(kf[0][1], qf[i][1], s0);
        f32x4 s1 = (f32x4){0.f, 0.f, 0.f, 0.f};
        s1 = mfma16(kf[1][0], qf[i][0], s1);
        s1 = mfma16(kf[1][1], qf[i][1], s1);
        float p0[4], p1[4];
#pragma unroll
        for (int r = 0; r < 4; ++r) {
          p0[r] = __builtin_amdgcn_exp2f(s0[r]);
          p1[r] = __builtin_amdgcn_exp2f(s1[r]);
        }
        lr[i] += ((p0[0] + p0[1]) + (p0[2] + p0[3])) +
                 ((p1[0] + p1[1]) + (p1[2] + p1[3]));
        uint4 pw;
        pw.x = pkbf(p0[0], p0[1]); pw.y = pkbf(p0[2], p0[3]);
        pw.z = pkbf(p1[0], p1[1]); pw.w = pkbf(p1[2], p1[3]);
        pfrag[i] = __builtin_bit_cast(bf16x8, pw);
      }
      // PV: o[q][d] += P[q][k]·V[k][d], K=32, P straight from registers
#pragma unroll
      for (int nv = 0; nv < 4; ++nv) {
        bf16x8 vb = *(const bf16x8*)(sV + (nv * 16 + lm) * 128 + (((p * 4 + quad) ^ lm) * 8));
        o[0][nv] = mfma16(pfrag[0], vb, o[0][nv]);
        o[1][nv] = mfma16(pfrag[1], vb, o[1][nv]);
      }
    }
    __syncthreads();
  }

  int b = bh >> 4, h = bh & 15;
#pragma unroll
  for (int i = 0; i < 2; ++i) {
    float ls = lr[i];
    ls += __shfl_xor(ls, 16);
    ls += __shfl_xor(ls, 32);
    float inv[4];
#pragma unroll
    for (int r = 0; r < 4; ++r)
      inv[r] = __builtin_amdgcn_rcpf(__shfl(ls, quad * 4 + r));
#pragma unroll
    for (int nv = 0; nv < 4; ++nv)
#pragma unroll
      for (int r = 0; r < 4; ++r) {
        int q = qt * 128 + w * 32 + i * 16 + quad * 4 + r;
        int d = nv * 16 + lm;
        Xw[((long)(b * 2048 + q) * 16 + h) * 64 + d] = f2bf(o[i][nv][r] * inv[r]);
      }
  }
}

// ---------- output GEMM: out = X @ Wo^T (pure bf16, fp32 out) ----------
__global__ __launch_bounds__(256) void out_gemm(
    const unsigned short* __restrict__ A, const unsigned short* __restrict__ Bw,
    float* __restrict__ C) {
  __shared__ __align__(16) unsigned short smem[8192]; // 16KB
  unsigned short* sA = smem;
  unsigned short* sB = smem + 4096;
  const int t = threadIdx.x;
  const int bm = blockIdx.x, bn = blockIdx.y;
  const int lane = t & 63, lm = lane & 15, quad = lane >> 4;
  const int w = t >> 6, wr = w >> 1, wc = w & 1;
  const int row = t >> 2, ch = t & 3;
  const int csrc = ((ch ^ ((t >> 3) & 3)) * 8);
  const int fsw = (lm >> 1) & 3;

  f32x4 acc[4][4];
#pragma unroll
  for (int i = 0; i < 4; ++i)
#pragma unroll
    for (int j = 0; j < 4; ++j) acc[i][j] = (f32x4){0.f, 0.f, 0.f, 0.f};

  for (int kk = 0; kk < 32; ++kk) {
    int kcol = kk * 32 + csrc;
#pragma unroll
    for (int half = 0; half < 2; ++half) {
      int r = half * 64 + row;
      int loff = (half * 256 + t) * 8;
      gl_lds16(A + (bm * 128 + r) * 1024 + kcol, sA + loff);
      gl_lds16(Bw + (bn * 128 + r) * 1024 + kcol, sB + loff);
    }
    __syncthreads();
    bf16x8 af[4], bf[4];
#pragma unroll
    for (int i = 0; i < 4; ++i) {
      int co = ((quad ^ fsw) * 8);
      af[i] = *(const bf16x8*)(sA + (wr * 64 + i * 16 + lm) * 32 + co);
      bf[i] = *(const bf16x8*)(sB + (wc * 64 + i * 16 + lm) * 32 + co);
    }
#pragma unroll
    for (int i = 0; i < 4; ++i)
#pragma unroll
      for (int j = 0; j < 4; ++j) acc[i][j] = mfma16(af[i], bf[j], acc[i][j]);
    __syncthreads();
  }
#pragma unroll
  for (int i = 0; i < 4; ++i)
#pragma unroll
    for (int j = 0; j < 4; ++j)
#pragma unroll
      for (int r = 0; r < 4; ++r) {
        int m = bm * 128 + wr * 64 + i * 16 + quad * 4 + r;
        int nn = bn * 128 + wc * 64 + j * 16 + lm;
        C[m * 1024 + nn] = acc[i][j][r];
      }
}

extern "C" void kernel_launch(void* const* d_in, const int* in_sizes, int n_in,
                              void* d_out, int out_size, void* d_ws, size_t ws_size,
                              hipStream_t stream) {
  const float* q  = (const float*)d_in[0];
  const float* k  = (const float*)d_in[1];
  const float* v  = (const float*)d_in[2];
  const float* Wq = (const float*)d_in[3];
  const float* Wk = (const float*)d_in[4];
  const float* Wv = (const float*)d_in[5];
  const float* Wo = (const float*)d_in[6];

  char* ws = (char*)d_ws;
  const size_t MK = (size_t)MROWS * DMODEL;   // 8,388,608 elems
  const size_t KK = (size_t)DMODEL * DMODEL;  // 1,048,576 elems
  size_t off = 0;
  auto nxt = [&](size_t elems) { unsigned short* p = (unsigned short*)(ws + off); off += elems * 2; return p; };
  unsigned short* q_b  = nxt(MK);
  unsigned short* k_b  = nxt(MK);
  unsigned short* v_b  = nxt(MK);
  unsigned short* Wq_b = nxt(KK);
  unsigned short* Wk_b = nxt(KK);
  unsigned short* Wv_b = nxt(KK);
  unsigned short* Wo_b = nxt(KK);
  unsigned short* Qw = nxt(MK);
  unsigned short* Kw = nxt(MK);
  unsigned short* Vt = nxt(MK);
  unsigned short* Xw = nxt(MK);
  (void)ws_size; (void)in_sizes; (void)n_in; (void)out_size;

  // (3*2097152 + 4*262144) float4-groups / 256 = 28672 blocks exactly
  cvt_all<<<28672, 256, 0, stream>>>(q, k, v, Wq, Wk, Wv, Wo,
                                     q_b, k_b, v_b, Wq_b, Wk_b, Wv_b, Wo_b);
  proj_gemm<<<dim3(64, 8, 3), 256, 0, stream>>>(q_b, k_b, v_b,
                                                Wq_b, Wk_b, Wv_b,
                                                Qw, Kw, Vt);
  flash_attn<<<dim3(64, 16), 256, 0, stream>>>(Qw, Kw, Vt, Xw);
  out_gemm<<<dim3(64, 8), 256, 0, stream>>>(Xw, Wo_b, (float*)d_out);
}

// Round 5
// 327.177 us; speedup vs baseline: 1.8266x; 1.1974x over previous
//
#include <hip/hip_runtime.h>
#include <stdint.h>

#define NHEAD 16
#define DKH 64
#define BBATCH 4
#define SEQ 2048
#define MROWS (BBATCH*SEQ)   // 8192
#define DMODEL 1024

typedef __attribute__((ext_vector_type(8))) __bf16 bf16x8;
typedef __attribute__((ext_vector_type(4))) float f32x4;

__device__ __forceinline__ unsigned short f2bf(float x) {
  unsigned int u = __float_as_uint(x);
  u += 0x7FFFu + ((u >> 16) & 1u);          // RN-even
  return (unsigned short)(u >> 16);
}
// pack bf16(a) | bf16(b)<<16, round-half-up: 2 adds + 1 v_perm
__device__ __forceinline__ unsigned int pkbf(float a, float b) {
  return __builtin_amdgcn_perm(__float_as_uint(b) + 0x8000u,
                               __float_as_uint(a) + 0x8000u, 0x07060302u);
}
// truncating pack (1 v_perm). Used only for P: downward bias cancels in
// softmax normalization because l sums the same truncated values.
__device__ __forceinline__ unsigned int pkbf_t(float a, float b) {
  return __builtin_amdgcn_perm(__float_as_uint(b), __float_as_uint(a), 0x07060302u);
}
__device__ __forceinline__ void gl_lds16(const void* g, void* l) {
  __builtin_amdgcn_global_load_lds(
      (const __attribute__((address_space(1))) unsigned int*)g,
      (__attribute__((address_space(3))) unsigned int*)l, 16, 0, 0);
}
__device__ __forceinline__ f32x4 mfma16(bf16x8 a, bf16x8 b, f32x4 c) {
  return __builtin_amdgcn_mfma_f32_16x16x32_bf16(a, b, c, 0, 0, 0);
}

// ---------- fused fp32 -> bf16 convert for all 7 tensors ----------
__global__ __launch_bounds__(256) void cvt_all(
    const float* __restrict__ s0, const float* __restrict__ s1,
    const float* __restrict__ s2, const float* __restrict__ s3,
    const float* __restrict__ s4, const float* __restrict__ s5,
    const float* __restrict__ s6,
    unsigned short* __restrict__ d0, unsigned short* __restrict__ d1,
    unsigned short* __restrict__ d2, unsigned short* __restrict__ d3,
    unsigned short* __restrict__ d4, unsigned short* __restrict__ d5,
    unsigned short* __restrict__ d6) {
  const int NB = 2097152;   // float4 groups in q/k/v
  const int NW = 262144;    // float4 groups in each W
  int i = blockIdx.x * 256 + threadIdx.x;
  const float* src; unsigned short* dst; int off;
  if      (i < NB)          { src = s0; dst = d0; off = i; }
  else if (i < 2*NB)        { src = s1; dst = d1; off = i - NB; }
  else if (i < 3*NB)        { src = s2; dst = d2; off = i - 2*NB; }
  else if (i < 3*NB + NW)   { src = s3; dst = d3; off = i - 3*NB; }
  else if (i < 3*NB + 2*NW) { src = s4; dst = d4; off = i - 3*NB - NW; }
  else if (i < 3*NB + 3*NW) { src = s5; dst = d5; off = i - 3*NB - 2*NW; }
  else                      { src = s6; dst = d6; off = i - 3*NB - 3*NW; }
  float4 x = ((const float4*)src)[off];
  uint2 o; o.x = pkbf(x.x, x.y); o.y = pkbf(x.z, x.w);
  ((uint2*)dst)[off] = o;
}

// ---------- fused Q/K/V projection GEMM: Y = X @ W^T (pure bf16) ----------
// z=0: Q -> [B,H,S,64] scaled by 0.125*log2e; z=1: K -> [B,H,S,64];
// z=2: V -> transposed [B,H,64,S].
__global__ __launch_bounds__(256) void proj_gemm(
    const unsigned short* __restrict__ A0, const unsigned short* __restrict__ A1,
    const unsigned short* __restrict__ A2,
    const unsigned short* __restrict__ B0, const unsigned short* __restrict__ B1,
    const unsigned short* __restrict__ B2,
    unsigned short* __restrict__ O0, unsigned short* __restrict__ O1,
    unsigned short* __restrict__ O2) {
  __shared__ __align__(16) unsigned short smem[16384]; // 32KB (transpose scratch in z=2)
  unsigned short* sA = smem;
  unsigned short* sB = smem + 4096;
  const int z = blockIdx.z;
  const unsigned short* Ah = (z == 0) ? A0 : ((z == 1) ? A1 : A2);
  const unsigned short* Bh = (z == 0) ? B0 : ((z == 1) ? B1 : B2);
  unsigned short* outp = (z == 0) ? O0 : ((z == 1) ? O1 : O2);
  const int t = threadIdx.x;
  const int bm = blockIdx.x, bn = blockIdx.y;
  const int lane = t & 63, lm = lane & 15, quad = lane >> 4;
  const int w = t >> 6, wr = w >> 1, wc = w & 1;
  const int row = t >> 2, ch = t & 3;
  const int csrc = ((ch ^ ((t >> 3) & 3)) * 8);  // staging swizzle
  const int fsw = (lm >> 1) & 3;                 // fragment-read swizzle

  f32x4 acc[4][4];
#pragma unroll
  for (int i = 0; i < 4; ++i)
#pragma unroll
    for (int j = 0; j < 4; ++j) acc[i][j] = (f32x4){0.f, 0.f, 0.f, 0.f};

  for (int kk = 0; kk < 32; ++kk) {
    int kcol = kk * 32 + csrc;
#pragma unroll
    for (int half = 0; half < 2; ++half) {
      int r = half * 64 + row;
      int loff = (half * 256 + t) * 8;
      gl_lds16(Ah + (bm * 128 + r) * 1024 + kcol, sA + loff);
      gl_lds16(Bh + (bn * 128 + r) * 1024 + kcol, sB + loff);
    }
    __syncthreads();
    bf16x8 af[4], bf[4];
#pragma unroll
    for (int i = 0; i < 4; ++i) {
      int co = ((quad ^ fsw) * 8);
      af[i] = *(const bf16x8*)(sA + (wr * 64 + i * 16 + lm) * 32 + co);
      bf[i] = *(const bf16x8*)(sB + (wc * 64 + i * 16 + lm) * 32 + co);
    }
#pragma unroll
    for (int i = 0; i < 4; ++i)
#pragma unroll
      for (int j = 0; j < 4; ++j) acc[i][j] = mfma16(af[i], bf[j], acc[i][j]);
    __syncthreads();
  }

  if (z < 2) {
    float scale = (z == 0) ? 0.125f * 1.44269504f : 1.0f;
#pragma unroll
    for (int i = 0; i < 4; ++i)
#pragma unroll
      for (int j = 0; j < 4; ++j)
#pragma unroll
        for (int r = 0; r < 4; ++r) {
          int m = bm * 128 + wr * 64 + i * 16 + quad * 4 + r;   // token
          int nn = bn * 128 + wc * 64 + j * 16 + lm;            // feature
          int b = m >> 11, s = m & 2047, h = nn >> 6, d = nn & 63;
          outp[((b * 16 + h) * 2048 + s) * 64 + d] = f2bf(acc[i][j][r] * scale);
        }
  } else {
    // V: transpose 128x128 tile through LDS, store [B,H,64,S]
    __syncthreads();
#pragma unroll
    for (int i = 0; i < 4; ++i)
#pragma unroll
      for (int j = 0; j < 4; ++j)
#pragma unroll
        for (int r = 0; r < 4; ++r) {
          int ml = wr * 64 + i * 16 + quad * 4 + r;
          int nl = wc * 64 + j * 16 + lm;
          smem[nl * 128 + ml] = f2bf(acc[i][j][r]);
        }
    __syncthreads();
    int nl = t >> 1, half = t & 1;
    int e = bn * 128 + nl, h = e >> 6, d = e & 63;
    int mg = bm * 128;
    int b = mg >> 11, s0 = (mg & 2047) + half * 64;
    const uint4* srcp = (const uint4*)(smem + nl * 128 + half * 64);
    uint4* dstp = (uint4*)(outp + ((b * 16 + h) * 64 + d) * 2048 + s0);
#pragma unroll
    for (int u = 0; u < 8; ++u) dstp[u] = srcp[u];
  }
}

// ---------- flash attention ----------
// Q[B,H,S,64] (pre-scaled by 0.125*log2e), K[B,H,S,64], V^T[B,H,64,S] -> X[B,S,H,64]
// grid (8,16,8): bh=(x<<3)|z, qt=y -> linear%8 = bh>>3, so each XCD owns
// heads 8x..8x+7 exclusively; hot K/V per XCD ~3MB < 4MB L2.
// S^T = K·Q^T with permuted K rows so P exits in the 16x16x32 A-operand layout.
// Direct exp2 (softmax shift-invariance; scores can't overflow fp32).
// launch_bounds (256,3): 84-VGPR no-spill point measured in R3; (256,4) spilled.
__global__ __launch_bounds__(256, 3) void flash_attn(
    const unsigned short* __restrict__ Qw, const unsigned short* __restrict__ Kw,
    const unsigned short* __restrict__ Vt, unsigned short* __restrict__ Xw) {
  __shared__ __align__(16) unsigned short sK[128 * 64];  // 16KB, swizzled s(r)
  __shared__ __align__(16) unsigned short sV[64 * 128];  // 16KB, [d][k], ^(row&15)
  const int t = threadIdx.x;
  const int bh = (blockIdx.x << 3) | blockIdx.z;
  const int qt = blockIdx.y;
  const int lane = t & 63, lm = lane & 15, quad = lane >> 4;
  const int w = t >> 6;

  // Q fragments straight from global (one-time, 64B/lane)
  const unsigned short* gq = Qw + (long)bh * SEQ * 64 + (long)qt * 128 * 64;
  bf16x8 qf[2][2];
#pragma unroll
  for (int i = 0; i < 2; ++i)
#pragma unroll
    for (int kc = 0; kc < 2; ++kc)
      qf[i][kc] = *(const bf16x8*)(gq + (w * 32 + i * 16 + lm) * 64 + kc * 32 + quad * 8);

  f32x4 o[2][4];
  float lr[2] = {0.f, 0.f};
#pragma unroll
  for (int i = 0; i < 2; ++i)
#pragma unroll
    for (int nv = 0; nv < 4; ++nv) o[i][nv] = (f32x4){0.f, 0.f, 0.f, 0.f};

  for (int kt = 0; kt < 16; ++kt) {
    const unsigned short* gk = Kw + (long)bh * SEQ * 64 + (long)kt * 128 * 64;
    const unsigned short* gv = Vt + (long)bh * 64 * SEQ + kt * 128;
#pragma unroll
    for (int is = 0; is < 4; ++is) {
      int cid = is * 256 + t;
      int rk = cid >> 3, ck = cid & 7;
      int srk = (rk & 3) | ((rk & 8) >> 1);
      gl_lds16(gk + rk * 64 + ((ck ^ srk) * 8), sK + cid * 8);
      int rv = cid >> 4, cv = cid & 15;
      gl_lds16(gv + rv * SEQ + ((cv ^ (rv & 15)) * 8), sV + cid * 8);
    }
    __syncthreads();

#pragma unroll
    for (int p = 0; p < 4; ++p) {
      // permuted K-row fragment reads (A-operand of S^T)
      bf16x8 kf[2][2];
#pragma unroll
      for (int tt = 0; tt < 2; ++tt) {
        int g = p * 32 + 8 * (lm >> 2) + (lm & 3) + 4 * tt;
        int sg = (g & 3) | ((g & 8) >> 1);
        kf[tt][0] = *(const bf16x8*)(sK + g * 64 + ((quad ^ sg) * 8));
        kf[tt][1] = *(const bf16x8*)(sK + g * 64 + (((4 + quad) ^ sg) * 8));
      }
      bf16x8 pfrag[2];
#pragma unroll
      for (int i = 0; i < 2; ++i) {
        f32x4 s0 = (f32x4){0.f, 0.f, 0.f, 0.f};
        s0 = mfma16(kf[0][0], qf[i][0], s0);
        s0 = mfma16(kf[0][1], qf[i][1], s0);
        f32x4 s1 = (f32x4){0.f, 0.f, 0.f, 0.f};
        s1 = mfma16(kf[1][0], qf[i][0], s1);
        s1 = mfma16(kf[1][1], qf[i][1], s1);
        float p0[4], p1[4];
#pragma unroll
        for (int r = 0; r < 4; ++r) {
          p0[r] = __builtin_amdgcn_exp2f(s0[r]);
          p1[r] = __builtin_amdgcn_exp2f(s1[r]);
        }
        lr[i] += ((p0[0] + p0[1]) + (p0[2] + p0[3])) +
                 ((p1[0] + p1[1]) + (p1[2] + p1[3]));
        uint4 pw;
        pw.x = pkbf_t(p0[0], p0[1]); pw.y = pkbf_t(p0[2], p0[3]);
        pw.z = pkbf_t(p1[0], p1[1]); pw.w = pkbf_t(p1[2], p1[3]);
        pfrag[i] = __builtin_bit_cast(bf16x8, pw);
      }
      // PV: o[q][d] += P[q][k]·V[k][d], K=32, P straight from registers
#pragma unroll
      for (int nv = 0; nv < 4; ++nv) {
        bf16x8 vb = *(const bf16x8*)(sV + (nv * 16 + lm) * 128 + (((p * 4 + quad) ^ lm) * 8));
        o[0][nv] = mfma16(pfrag[0], vb, o[0][nv]);
        o[1][nv] = mfma16(pfrag[1], vb, o[1][nv]);
      }
    }
    __syncthreads();
  }

  int b = bh >> 4, h = bh & 15;
#pragma unroll
  for (int i = 0; i < 2; ++i) {
    float ls = lr[i];
    ls += __shfl_xor(ls, 16);
    ls += __shfl_xor(ls, 32);
    float inv[4];
#pragma unroll
    for (int r = 0; r < 4; ++r)
      inv[r] = __builtin_amdgcn_rcpf(__shfl(ls, quad * 4 + r));
#pragma unroll
    for (int nv = 0; nv < 4; ++nv)
#pragma unroll
      for (int r = 0; r < 4; ++r) {
        int q = qt * 128 + w * 32 + i * 16 + quad * 4 + r;
        int d = nv * 16 + lm;
        Xw[((long)(b * 2048 + q) * 16 + h) * 64 + d] = f2bf(o[i][nv][r] * inv[r]);
      }
  }
}

// ---------- output GEMM: out = X @ Wo^T (pure bf16, fp32 out) ----------
__global__ __launch_bounds__(256) void out_gemm(
    const unsigned short* __restrict__ A, const unsigned short* __restrict__ Bw,
    float* __restrict__ C) {
  __shared__ __align__(16) unsigned short smem[8192]; // 16KB
  unsigned short* sA = smem;
  unsigned short* sB = smem + 4096;
  const int t = threadIdx.x;
  const int bm = blockIdx.x, bn = blockIdx.y;
  const int lane = t & 63, lm = lane & 15, quad = lane >> 4;
  const int w = t >> 6, wr = w >> 1, wc = w & 1;
  const int row = t >> 2, ch = t & 3;
  const int csrc = ((ch ^ ((t >> 3) & 3)) * 8);
  const int fsw = (lm >> 1) & 3;

  f32x4 acc[4][4];
#pragma unroll
  for (int i = 0; i < 4; ++i)
#pragma unroll
    for (int j = 0; j < 4; ++j) acc[i][j] = (f32x4){0.f, 0.f, 0.f, 0.f};

  for (int kk = 0; kk < 32; ++kk) {
    int kcol = kk * 32 + csrc;
#pragma unroll
    for (int half = 0; half < 2; ++half) {
      int r = half * 64 + row;
      int loff = (half * 256 + t) * 8;
      gl_lds16(A + (bm * 128 + r) * 1024 + kcol, sA + loff);
      gl_lds16(Bw + (bn * 128 + r) * 1024 + kcol, sB + loff);
    }
    __syncthreads();
    bf16x8 af[4], bf[4];
#pragma unroll
    for (int i = 0; i < 4; ++i) {
      int co = ((quad ^ fsw) * 8);
      af[i] = *(const bf16x8*)(sA + (wr * 64 + i * 16 + lm) * 32 + co);
      bf[i] = *(const bf16x8*)(sB + (wc * 64 + i * 16 + lm) * 32 + co);
    }
#pragma unroll
    for (int i = 0; i < 4; ++i)
#pragma unroll
      for (int j = 0; j < 4; ++j) acc[i][j] = mfma16(af[i], bf[j], acc[i][j]);
    __syncthreads();
  }
#pragma unroll
  for (int i = 0; i < 4; ++i)
#pragma unroll
    for (int j = 0; j < 4; ++j)
#pragma unroll
      for (int r = 0; r < 4; ++r) {
        int m = bm * 128 + wr * 64 + i * 16 + quad * 4 + r;
        int nn = bn * 128 + wc * 64 + j * 16 + lm;
        C[m * 1024 + nn] = acc[i][j][r];
      }
}

extern "C" void kernel_launch(void* const* d_in, const int* in_sizes, int n_in,
                              void* d_out, int out_size, void* d_ws, size_t ws_size,
                              hipStream_t stream) {
  const float* q  = (const float*)d_in[0];
  const float* k  = (const float*)d_in[1];
  const float* v  = (const float*)d_in[2];
  const float* Wq = (const float*)d_in[3];
  const float* Wk = (const float*)d_in[4];
  const float* Wv = (const float*)d_in[5];
  const float* Wo = (const float*)d_in[6];

  char* ws = (char*)d_ws;
  const size_t MK = (size_t)MROWS * DMODEL;   // 8,388,608 elems
  const size_t KK = (size_t)DMODEL * DMODEL;  // 1,048,576 elems
  size_t off = 0;
  auto nxt = [&](size_t elems) { unsigned short* p = (unsigned short*)(ws + off); off += elems * 2; return p; };
  unsigned short* q_b  = nxt(MK);
  unsigned short* k_b  = nxt(MK);
  unsigned short* v_b  = nxt(MK);
  unsigned short* Wq_b = nxt(KK);
  unsigned short* Wk_b = nxt(KK);
  unsigned short* Wv_b = nxt(KK);
  unsigned short* Wo_b = nxt(KK);
  unsigned short* Qw = nxt(MK);
  unsigned short* Kw = nxt(MK);
  unsigned short* Vt = nxt(MK);
  unsigned short* Xw = nxt(MK);
  (void)ws_size; (void)in_sizes; (void)n_in; (void)out_size;

  // (3*2097152 + 4*262144) float4-groups / 256 = 28672 blocks exactly
  cvt_all<<<28672, 256, 0, stream>>>(q, k, v, Wq, Wk, Wv, Wo,
                                     q_b, k_b, v_b, Wq_b, Wk_b, Wv_b, Wo_b);
  proj_gemm<<<dim3(64, 8, 3), 256, 0, stream>>>(q_b, k_b, v_b,
                                                Wq_b, Wk_b, Wv_b,
                                                Qw, Kw, Vt);
  flash_attn<<<dim3(8, 16, 8), 256, 0, stream>>>(Qw, Kw, Vt, Xw);
  out_gemm<<<dim3(64, 8), 256, 0, stream>>>(Xw, Wo_b, (float*)d_out);
}

// Round 6
// 316.250 us; speedup vs baseline: 1.8897x; 1.0346x over previous
//
#include <hip/hip_runtime.h>
#include <stdint.h>

#define NHEAD 16
#define DKH 64
#define BBATCH 4
#define SEQ 2048
#define MROWS (BBATCH*SEQ)   // 8192
#define DMODEL 1024

typedef __attribute__((ext_vector_type(8))) __bf16 bf16x8;
typedef __attribute__((ext_vector_type(4))) float f32x4;

__device__ __forceinline__ unsigned short f2bf(float x) {
  unsigned int u = __float_as_uint(x);
  u += 0x7FFFu + ((u >> 16) & 1u);          // RN-even
  return (unsigned short)(u >> 16);
}
// pack bf16(a) | bf16(b)<<16, round-half-up: 2 adds + 1 v_perm
__device__ __forceinline__ unsigned int pkbf(float a, float b) {
  return __builtin_amdgcn_perm(__float_as_uint(b) + 0x8000u,
                               __float_as_uint(a) + 0x8000u, 0x07060302u);
}
// truncating pack (1 v_perm). Used only for P: downward bias cancels in
// softmax normalization because l sums the same truncated values.
__device__ __forceinline__ unsigned int pkbf_t(float a, float b) {
  return __builtin_amdgcn_perm(__float_as_uint(b), __float_as_uint(a), 0x07060302u);
}
__device__ __forceinline__ void gl_lds16(const void* g, void* l) {
  __builtin_amdgcn_global_load_lds(
      (const __attribute__((address_space(1))) unsigned int*)g,
      (__attribute__((address_space(3))) unsigned int*)l, 16, 0, 0);
}
__device__ __forceinline__ f32x4 mfma16(bf16x8 a, bf16x8 b, f32x4 c) {
  return __builtin_amdgcn_mfma_f32_16x16x32_bf16(a, b, c, 0, 0, 0);
}

// ---------- fused fp32 -> bf16 convert for all 7 tensors ----------
__global__ __launch_bounds__(256) void cvt_all(
    const float* __restrict__ s0, const float* __restrict__ s1,
    const float* __restrict__ s2, const float* __restrict__ s3,
    const float* __restrict__ s4, const float* __restrict__ s5,
    const float* __restrict__ s6,
    unsigned short* __restrict__ d0, unsigned short* __restrict__ d1,
    unsigned short* __restrict__ d2, unsigned short* __restrict__ d3,
    unsigned short* __restrict__ d4, unsigned short* __restrict__ d5,
    unsigned short* __restrict__ d6) {
  const int NB = 2097152;   // float4 groups in q/k/v
  const int NW = 262144;    // float4 groups in each W
  int i = blockIdx.x * 256 + threadIdx.x;
  const float* src; unsigned short* dst; int off;
  if      (i < NB)          { src = s0; dst = d0; off = i; }
  else if (i < 2*NB)        { src = s1; dst = d1; off = i - NB; }
  else if (i < 3*NB)        { src = s2; dst = d2; off = i - 2*NB; }
  else if (i < 3*NB + NW)   { src = s3; dst = d3; off = i - 3*NB; }
  else if (i < 3*NB + 2*NW) { src = s4; dst = d4; off = i - 3*NB - NW; }
  else if (i < 3*NB + 3*NW) { src = s5; dst = d5; off = i - 3*NB - 2*NW; }
  else                      { src = s6; dst = d6; off = i - 3*NB - 3*NW; }
  float4 x = ((const float4*)src)[off];
  uint2 o; o.x = pkbf(x.x, x.y); o.y = pkbf(x.z, x.w);
  ((uint2*)dst)[off] = o;
}

// ---------- fused Q/K/V projection GEMM: Y = X @ W^T (pure bf16) ----------
// BK=64: 16 barrier pairs (vs 32 at BK=32), 32 MFMA per barrier.
// LDS rows of 64 elems, 8 chunks of 8; slot s of row r holds source chunk
// s ^ (r&7) -> conflict-free staging AND fragment reads.
// z=0: Q -> [B,H,S,64] scaled by 0.125*log2e; z=1: K; z=2: V^T [B,H,64,S].
__global__ __launch_bounds__(256) void proj_gemm(
    const unsigned short* __restrict__ A0, const unsigned short* __restrict__ A1,
    const unsigned short* __restrict__ A2,
    const unsigned short* __restrict__ B0, const unsigned short* __restrict__ B1,
    const unsigned short* __restrict__ B2,
    unsigned short* __restrict__ O0, unsigned short* __restrict__ O1,
    unsigned short* __restrict__ O2) {
  __shared__ __align__(16) unsigned short smem[16384]; // 32KB (also transpose scratch, z=2)
  unsigned short* sA = smem;
  unsigned short* sB = smem + 8192;
  const int z = blockIdx.z;
  const unsigned short* Ah = (z == 0) ? A0 : ((z == 1) ? A1 : A2);
  const unsigned short* Bh = (z == 0) ? B0 : ((z == 1) ? B1 : B2);
  unsigned short* outp = (z == 0) ? O0 : ((z == 1) ? O1 : O2);
  const int t = threadIdx.x;
  const int bm = blockIdx.x, bn = blockIdx.y;
  const int lane = t & 63, lm = lane & 15, quad = lane >> 4;
  const int w = t >> 6, wr = w >> 1, wc = w & 1;

  f32x4 acc[4][4];
#pragma unroll
  for (int i = 0; i < 4; ++i)
#pragma unroll
    for (int j = 0; j < 4; ++j) acc[i][j] = (f32x4){0.f, 0.f, 0.f, 0.f};

  for (int kk = 0; kk < 16; ++kk) {
#pragma unroll
    for (int jj = 0; jj < 4; ++jj) {
      int cid = jj * 256 + t;              // 0..1023
      int r = cid >> 3, c = cid & 7;
      int gcol = kk * 64 + ((c ^ (r & 7)) * 8);
      gl_lds16(Ah + (bm * 128 + r) * 1024 + gcol, sA + cid * 8);
      gl_lds16(Bh + (bn * 128 + r) * 1024 + gcol, sB + cid * 8);
    }
    __syncthreads();
#pragma unroll
    for (int kc = 0; kc < 2; ++kc) {
      bf16x8 af[4], bf[4];
#pragma unroll
      for (int i = 0; i < 4; ++i) {
        int m = wr * 64 + i * 16 + lm;
        int nn = wc * 64 + i * 16 + lm;
        int slot = ((kc * 4 + quad) ^ (lm & 7)) * 8;
        af[i] = *(const bf16x8*)(sA + m * 64 + slot);
        bf[i] = *(const bf16x8*)(sB + nn * 64 + slot);
      }
#pragma unroll
      for (int i = 0; i < 4; ++i)
#pragma unroll
        for (int j = 0; j < 4; ++j) acc[i][j] = mfma16(af[i], bf[j], acc[i][j]);
    }
    __syncthreads();
  }

  if (z < 2) {
    float scale = (z == 0) ? 0.125f * 1.44269504f : 1.0f;
#pragma unroll
    for (int i = 0; i < 4; ++i)
#pragma unroll
      for (int j = 0; j < 4; ++j)
#pragma unroll
        for (int r = 0; r < 4; ++r) {
          int m = bm * 128 + wr * 64 + i * 16 + quad * 4 + r;   // token
          int nn = bn * 128 + wc * 64 + j * 16 + lm;            // feature
          int b = m >> 11, s = m & 2047, h = nn >> 6, d = nn & 63;
          outp[((b * 16 + h) * 2048 + s) * 64 + d] = f2bf(acc[i][j][r] * scale);
        }
  } else {
    // V: transpose 128x128 tile through LDS (chunk-XOR mask 15), store [B,H,64,S]
#pragma unroll
    for (int i = 0; i < 4; ++i)
#pragma unroll
      for (int j = 0; j < 4; ++j)
#pragma unroll
        for (int r = 0; r < 4; ++r) {
          int ml = wr * 64 + i * 16 + quad * 4 + r;   // token (col of scratch)
          int nl = wc * 64 + j * 16 + lm;             // feature (row of scratch)
          smem[nl * 128 + (((ml >> 3) ^ (nl & 15)) << 3) + (ml & 7)] =
              f2bf(acc[i][j][r]);
        }
    __syncthreads();
    int nl = t >> 1, half = t & 1;
    int e = bn * 128 + nl, h = e >> 6, d = e & 63;
    int mg = bm * 128;
    int b = mg >> 11, s0 = mg & 2047;
    uint4* dstp = (uint4*)(outp + ((b * 16 + h) * 64 + d) * 2048 + s0);
#pragma unroll
    for (int u = 0; u < 8; ++u) {
      int c = half * 8 + u;                 // token chunk 0..15
      int slot = c ^ (nl & 15);
      dstp[c] = *(const uint4*)(smem + nl * 128 + slot * 8);
    }
  }
}

// ---------- flash attention ----------
// Q[B,H,S,64] (pre-scaled by 0.125*log2e), K[B,H,S,64], V^T[B,H,64,S] -> X[B,S,H,64]
// grid (8,16,8): bh=(x<<3)|z, qt=y -> linear%8 = bh>>3, so each XCD owns
// heads 8x..8x+7 exclusively; hot K/V per XCD ~3MB < 4MB L2.
// S^T = K·Q^T with permuted K rows so P exits in the 16x16x32 A-operand layout.
// Direct exp2 (softmax shift-invariance; scores can't overflow fp32).
// launch_bounds (256,3): 84-VGPR no-spill point measured in R3; (256,4) spilled.
__global__ __launch_bounds__(256, 3) void flash_attn(
    const unsigned short* __restrict__ Qw, const unsigned short* __restrict__ Kw,
    const unsigned short* __restrict__ Vt, unsigned short* __restrict__ Xw) {
  __shared__ __align__(16) unsigned short sK[128 * 64];  // 16KB, swizzled s(r)
  __shared__ __align__(16) unsigned short sV[64 * 128];  // 16KB, [d][k], ^(row&15)
  const int t = threadIdx.x;
  const int bh = (blockIdx.x << 3) | blockIdx.z;
  const int qt = blockIdx.y;
  const int lane = t & 63, lm = lane & 15, quad = lane >> 4;
  const int w = t >> 6;

  // Q fragments straight from global (one-time, 64B/lane)
  const unsigned short* gq = Qw + (long)bh * SEQ * 64 + (long)qt * 128 * 64;
  bf16x8 qf[2][2];
#pragma unroll
  for (int i = 0; i < 2; ++i)
#pragma unroll
    for (int kc = 0; kc < 2; ++kc)
      qf[i][kc] = *(const bf16x8*)(gq + (w * 32 + i * 16 + lm) * 64 + kc * 32 + quad * 8);

  f32x4 o[2][4];
  float lr[2] = {0.f, 0.f};
#pragma unroll
  for (int i = 0; i < 2; ++i)
#pragma unroll
    for (int nv = 0; nv < 4; ++nv) o[i][nv] = (f32x4){0.f, 0.f, 0.f, 0.f};

  for (int kt = 0; kt < 16; ++kt) {
    const unsigned short* gk = Kw + (long)bh * SEQ * 64 + (long)kt * 128 * 64;
    const unsigned short* gv = Vt + (long)bh * 64 * SEQ + kt * 128;
#pragma unroll
    for (int is = 0; is < 4; ++is) {
      int cid = is * 256 + t;
      int rk = cid >> 3, ck = cid & 7;
      int srk = (rk & 3) | ((rk & 8) >> 1);
      gl_lds16(gk + rk * 64 + ((ck ^ srk) * 8), sK + cid * 8);
      int rv = cid >> 4, cv = cid & 15;
      gl_lds16(gv + rv * SEQ + ((cv ^ (rv & 15)) * 8), sV + cid * 8);
    }
    __syncthreads();

#pragma unroll
    for (int p = 0; p < 4; ++p) {
      // permuted K-row fragment reads (A-operand of S^T)
      bf16x8 kf[2][2];
#pragma unroll
      for (int tt = 0; tt < 2; ++tt) {
        int g = p * 32 + 8 * (lm >> 2) + (lm & 3) + 4 * tt;
        int sg = (g & 3) | ((g & 8) >> 1);
        kf[tt][0] = *(const bf16x8*)(sK + g * 64 + ((quad ^ sg) * 8));
        kf[tt][1] = *(const bf16x8*)(sK + g * 64 + (((4 + quad) ^ sg) * 8));
      }
      bf16x8 pfrag[2];
#pragma unroll
      for (int i = 0; i < 2; ++i) {
        f32x4 s0 = (f32x4){0.f, 0.f, 0.f, 0.f};
        s0 = mfma16(kf[0][0], qf[i][0], s0);
        s0 = mfma16(kf[0][1], qf[i][1], s0);
        f32x4 s1 = (f32x4){0.f, 0.f, 0.f, 0.f};
        s1 = mfma16(kf[1][0], qf[i][0], s1);
        s1 = mfma16(kf[1][1], qf[i][1], s1);
        float p0[4], p1[4];
#pragma unroll
        for (int r = 0; r < 4; ++r) {
          p0[r] = __builtin_amdgcn_exp2f(s0[r]);
          p1[r] = __builtin_amdgcn_exp2f(s1[r]);
        }
        lr[i] += ((p0[0] + p0[1]) + (p0[2] + p0[3])) +
                 ((p1[0] + p1[1]) + (p1[2] + p1[3]));
        uint4 pw;
        pw.x = pkbf_t(p0[0], p0[1]); pw.y = pkbf_t(p0[2], p0[3]);
        pw.z = pkbf_t(p1[0], p1[1]); pw.w = pkbf_t(p1[2], p1[3]);
        pfrag[i] = __builtin_bit_cast(bf16x8, pw);
      }
      // PV: o[q][d] += P[q][k]·V[k][d], K=32, P straight from registers
#pragma unroll
      for (int nv = 0; nv < 4; ++nv) {
        bf16x8 vb = *(const bf16x8*)(sV + (nv * 16 + lm) * 128 + (((p * 4 + quad) ^ lm) * 8));
        o[0][nv] = mfma16(pfrag[0], vb, o[0][nv]);
        o[1][nv] = mfma16(pfrag[1], vb, o[1][nv]);
      }
    }
    __syncthreads();
  }

  int b = bh >> 4, h = bh & 15;
#pragma unroll
  for (int i = 0; i < 2; ++i) {
    float ls = lr[i];
    ls += __shfl_xor(ls, 16);
    ls += __shfl_xor(ls, 32);
    float inv[4];
#pragma unroll
    for (int r = 0; r < 4; ++r)
      inv[r] = __builtin_amdgcn_rcpf(__shfl(ls, quad * 4 + r));
#pragma unroll
    for (int nv = 0; nv < 4; ++nv)
#pragma unroll
      for (int r = 0; r < 4; ++r) {
        int q = qt * 128 + w * 32 + i * 16 + quad * 4 + r;
        int d = nv * 16 + lm;
        Xw[((long)(b * 2048 + q) * 16 + h) * 64 + d] = f2bf(o[i][nv][r] * inv[r]);
      }
  }
}

// ---------- output GEMM: out = X @ Wo^T (pure bf16, fp32 out, BK=64) ----------
__global__ __launch_bounds__(256) void out_gemm(
    const unsigned short* __restrict__ A, const unsigned short* __restrict__ Bw,
    float* __restrict__ C) {
  __shared__ __align__(16) unsigned short smem[16384]; // 32KB
  unsigned short* sA = smem;
  unsigned short* sB = smem + 8192;
  const int t = threadIdx.x;
  const int bm = blockIdx.x, bn = blockIdx.y;
  const int lane = t & 63, lm = lane & 15, quad = lane >> 4;
  const int w = t >> 6, wr = w >> 1, wc = w & 1;

  f32x4 acc[4][4];
#pragma unroll
  for (int i = 0; i < 4; ++i)
#pragma unroll
    for (int j = 0; j < 4; ++j) acc[i][j] = (f32x4){0.f, 0.f, 0.f, 0.f};

  for (int kk = 0; kk < 16; ++kk) {
#pragma unroll
    for (int jj = 0; jj < 4; ++jj) {
      int cid = jj * 256 + t;
      int r = cid >> 3, c = cid & 7;
      int gcol = kk * 64 + ((c ^ (r & 7)) * 8);
      gl_lds16(A + (bm * 128 + r) * 1024 + gcol, sA + cid * 8);
      gl_lds16(Bw + (bn * 128 + r) * 1024 + gcol, sB + cid * 8);
    }
    __syncthreads();
#pragma unroll
    for (int kc = 0; kc < 2; ++kc) {
      bf16x8 af[4], bf[4];
#pragma unroll
      for (int i = 0; i < 4; ++i) {
        int m = wr * 64 + i * 16 + lm;
        int nn = wc * 64 + i * 16 + lm;
        int slot = ((kc * 4 + quad) ^ (lm & 7)) * 8;
        af[i] = *(const bf16x8*)(sA + m * 64 + slot);
        bf[i] = *(const bf16x8*)(sB + nn * 64 + slot);
      }
#pragma unroll
      for (int i = 0; i < 4; ++i)
#pragma unroll
        for (int j = 0; j < 4; ++j) acc[i][j] = mfma16(af[i], bf[j], acc[i][j]);
    }
    __syncthreads();
  }
#pragma unroll
  for (int i = 0; i < 4; ++i)
#pragma unroll
    for (int j = 0; j < 4; ++j)
#pragma unroll
      for (int r = 0; r < 4; ++r) {
        int m = bm * 128 + wr * 64 + i * 16 + quad * 4 + r;
        int nn = bn * 128 + wc * 64 + j * 16 + lm;
        C[m * 1024 + nn] = acc[i][j][r];
      }
}

extern "C" void kernel_launch(void* const* d_in, const int* in_sizes, int n_in,
                              void* d_out, int out_size, void* d_ws, size_t ws_size,
                              hipStream_t stream) {
  const float* q  = (const float*)d_in[0];
  const float* k  = (const float*)d_in[1];
  const float* v  = (const float*)d_in[2];
  const float* Wq = (const float*)d_in[3];
  const float* Wk = (const float*)d_in[4];
  const float* Wv = (const float*)d_in[5];
  const float* Wo = (const float*)d_in[6];

  char* ws = (char*)d_ws;
  const size_t MK = (size_t)MROWS * DMODEL;   // 8,388,608 elems
  const size_t KK = (size_t)DMODEL * DMODEL;  // 1,048,576 elems
  size_t off = 0;
  auto nxt = [&](size_t elems) { unsigned short* p = (unsigned short*)(ws + off); off += elems * 2; return p; };
  unsigned short* q_b  = nxt(MK);
  unsigned short* k_b  = nxt(MK);
  unsigned short* v_b  = nxt(MK);
  unsigned short* Wq_b = nxt(KK);
  unsigned short* Wk_b = nxt(KK);
  unsigned short* Wv_b = nxt(KK);
  unsigned short* Wo_b = nxt(KK);
  unsigned short* Qw = nxt(MK);
  unsigned short* Kw = nxt(MK);
  unsigned short* Vt = nxt(MK);
  unsigned short* Xw = nxt(MK);
  (void)ws_size; (void)in_sizes; (void)n_in; (void)out_size;

  // (3*2097152 + 4*262144) float4-groups / 256 = 28672 blocks exactly
  cvt_all<<<28672, 256, 0, stream>>>(q, k, v, Wq, Wk, Wv, Wo,
                                     q_b, k_b, v_b, Wq_b, Wk_b, Wv_b, Wo_b);
  proj_gemm<<<dim3(64, 8, 3), 256, 0, stream>>>(q_b, k_b, v_b,
                                                Wq_b, Wk_b, Wv_b,
                                                Qw, Kw, Vt);
  flash_attn<<<dim3(8, 16, 8), 256, 0, stream>>>(Qw, Kw, Vt, Xw);
  out_gemm<<<dim3(64, 8), 256, 0, stream>>>(Xw, Wo_b, (float*)d_out);
}